// Round 2
// baseline (74.418 us; speedup 1.0000x reference)
//
#include <hip/hip_runtime.h>
#include <math.h>

#define BATCH 8192
#define WALK  91      // L + 1 + L_NS = 80 + 1 + 10
#define LVAL  80
#define DIM   128
#define ROWS_PER_BLOCK 4

// One wave (64 lanes) per batch row; lane covers 2 of the 128 dims.
__global__ __launch_bounds__(256, 8)
void node2vec_loss_kernel(const float* __restrict__ X,
                          const int* __restrict__ rw,   // int32 indices (JAX x64 off)
                          float* __restrict__ row_loss) {
    __shared__ int s_idx[ROWS_PER_BLOCK * WALK];

    const int wave = threadIdx.x >> 6;
    const int lane = threadIdx.x & 63;
    const int row_base = blockIdx.x * ROWS_PER_BLOCK;

    // Cooperative, coalesced load of the 4 rows' walk indices into LDS.
    for (int i = threadIdx.x; i < ROWS_PER_BLOCK * WALK; i += 256) {
        s_idx[i] = rw[row_base * WALK + i];
    }
    __syncthreads();

    const int* my_idx = s_idx + wave * WALK;
    const int b = row_base + wave;

    // Start-node embedding fragment (2 floats per lane), kept in registers.
    const long long idx0 = (long long)my_idx[0];
    const float2 xs = *(const float2*)(X + idx0 * DIM + lane * 2);

    float sumexp = 0.0f;
    float num = 0.0f;

    // 91 = 13 chunks of 7: issue 7 independent gathers, then reduce 7 scores.
    for (int k0 = 0; k0 < WALK; k0 += 7) {
        float2 v[7];
        #pragma unroll
        for (int j = 0; j < 7; ++j) {
            const long long idx = (long long)my_idx[k0 + j];
            v[j] = *(const float2*)(X + idx * DIM + lane * 2);
        }
        #pragma unroll
        for (int j = 0; j < 7; ++j) {
            float p = v[j].x * xs.x + v[j].y * xs.y;
            // 64-lane butterfly sum (all lanes end with the full dot product)
            p += __shfl_xor(p, 1);
            p += __shfl_xor(p, 2);
            p += __shfl_xor(p, 4);
            p += __shfl_xor(p, 8);
            p += __shfl_xor(p, 16);
            p += __shfl_xor(p, 32);
            sumexp += expf(p);
            const int k = k0 + j;
            if (k >= 1 && k <= LVAL) num += p;
        }
    }

    if (lane == 0) {
        row_loss[b] = (float)LVAL * logf(sumexp) - num;
    }
}

// Deterministic single-block mean over the 8192 per-row losses.
__global__ __launch_bounds__(256)
void reduce_mean_kernel(const float* __restrict__ row_loss,
                        float* __restrict__ out) {
    __shared__ double sdata[256];
    double acc = 0.0;
    for (int i = threadIdx.x; i < BATCH; i += 256) {
        acc += (double)row_loss[i];
    }
    sdata[threadIdx.x] = acc;
    __syncthreads();
    for (int s = 128; s > 0; s >>= 1) {
        if ((int)threadIdx.x < s) sdata[threadIdx.x] += sdata[threadIdx.x + s];
        __syncthreads();
    }
    if (threadIdx.x == 0) {
        out[0] = (float)(sdata[0] / (double)BATCH);
    }
}

extern "C" void kernel_launch(void* const* d_in, const int* in_sizes, int n_in,
                              void* d_out, int out_size, void* d_ws, size_t ws_size,
                              hipStream_t stream) {
    const float* X = (const float*)d_in[0];
    const int* rw = (const int*)d_in[1];
    // d_in[2] is l == 80, a compile-time constant here (LVAL).
    float* row_loss = (float*)d_ws;   // 8192 floats = 32 KB scratch
    float* out = (float*)d_out;

    node2vec_loss_kernel<<<BATCH / ROWS_PER_BLOCK, 256, 0, stream>>>(X, rw, row_loss);
    reduce_mean_kernel<<<1, 256, 0, stream>>>(row_loss, out);
}

// Round 3
// 71.257 us; speedup vs baseline: 1.0444x; 1.0444x over previous
//
#include <hip/hip_runtime.h>
#include <math.h>

#define BATCH 8192
#define WALK  91      // L + 1 + L_NS = 80 + 1 + 10
#define LVAL  80
#define DIM   128
#define ROWS_PER_BLOCK 4

// One wave (64 lanes) per batch row.
// 16 lanes per walk entry (8 dims each, 2x float4); wave covers 4 entries/iter.
__global__ __launch_bounds__(256, 8)
void node2vec_loss_kernel(const float* __restrict__ X,
                          const int* __restrict__ rw,   // int32 indices (JAX x64 off)
                          float* __restrict__ row_loss) {
    __shared__ int s_idx[ROWS_PER_BLOCK * WALK];

    const int wave = threadIdx.x >> 6;
    const int lane = threadIdx.x & 63;
    const int grp  = lane >> 4;       // 0..3: which walk entry in the quad
    const int sub  = lane & 15;       // 0..15: which 8-dim slice
    const int row_base = blockIdx.x * ROWS_PER_BLOCK;

    // Cooperative, coalesced load of the 4 rows' walk indices into LDS.
    for (int i = threadIdx.x; i < ROWS_PER_BLOCK * WALK; i += 256) {
        s_idx[i] = rw[row_base * WALK + i];
    }
    __syncthreads();

    const int* my_idx = s_idx + wave * WALK;
    const int b = row_base + wave;

    // Start-node fragment: dims [sub*8, sub*8+8) in registers.
    const size_t idx0 = (size_t)my_idx[0];
    const float4 xs0 = *(const float4*)(X + idx0 * DIM + sub * 8);
    const float4 xs1 = *(const float4*)(X + idx0 * DIM + sub * 8 + 4);

    float sumexp = 0.0f;   // per-lane: sum over this group's k's (lanes in a
    float num    = 0.0f;   // group hold identical values after the butterfly)

    // 23 quads cover k = 0..91; k == 91 is masked out.
    #pragma unroll 4
    for (int i = 0; i < 23; ++i) {
        const int k = i * 4 + grp;
        const int kc = (k < WALK) ? k : 0;          // safe index for the pad slot
        const size_t idx = (size_t)my_idx[kc];
        const float4* base = (const float4*)(X + idx * DIM + sub * 8);
        const float4 a = base[0];
        const float4 c = base[1];

        float p = a.x * xs0.x + a.y * xs0.y + a.z * xs0.z + a.w * xs0.w
                + c.x * xs1.x + c.y * xs1.y + c.z * xs1.z + c.w * xs1.w;
        // Reduce over the 16 lanes of this group (xor bits 0..3 stay in-group).
        p += __shfl_xor(p, 1);
        p += __shfl_xor(p, 2);
        p += __shfl_xor(p, 4);
        p += __shfl_xor(p, 8);

        if (k < WALK) {
            sumexp += __expf(p);
            if (k >= 1 && k <= LVAL) num += p;
        }
    }

    // Combine the 4 groups' partial sums across the wave.
    sumexp += __shfl_xor(sumexp, 16);
    sumexp += __shfl_xor(sumexp, 32);
    num    += __shfl_xor(num, 16);
    num    += __shfl_xor(num, 32);

    if (lane == 0) {
        row_loss[b] = (float)LVAL * __logf(sumexp) - num;
    }
}

// Deterministic single-block mean over the 8192 per-row losses.
__global__ __launch_bounds__(256)
void reduce_mean_kernel(const float* __restrict__ row_loss,
                        float* __restrict__ out) {
    __shared__ double sdata[256];
    double acc = 0.0;
    for (int i = threadIdx.x; i < BATCH; i += 256) {
        acc += (double)row_loss[i];
    }
    sdata[threadIdx.x] = acc;
    __syncthreads();
    for (int s = 128; s > 0; s >>= 1) {
        if ((int)threadIdx.x < s) sdata[threadIdx.x] += sdata[threadIdx.x + s];
        __syncthreads();
    }
    if (threadIdx.x == 0) {
        out[0] = (float)(sdata[0] / (double)BATCH);
    }
}

extern "C" void kernel_launch(void* const* d_in, const int* in_sizes, int n_in,
                              void* d_out, int out_size, void* d_ws, size_t ws_size,
                              hipStream_t stream) {
    const float* X = (const float*)d_in[0];
    const int* rw = (const int*)d_in[1];
    // d_in[2] is l == 80, a compile-time constant here (LVAL).
    float* row_loss = (float*)d_ws;   // 8192 floats = 32 KB scratch
    float* out = (float*)d_out;

    node2vec_loss_kernel<<<BATCH / ROWS_PER_BLOCK, 256, 0, stream>>>(X, rw, row_loss);
    reduce_mean_kernel<<<1, 256, 0, stream>>>(row_loss, out);
}